// Round 1
// baseline (623.155 us; speedup 1.0000x reference)
//
#include <hip/hip_runtime.h>
#include <math.h>

#define DC_C 6
#define DV_C 3

// Build check-slot adjacency: for each edge e, claim a slot j in its check c,
// record pos[e] = c*6+j, and scatter the initial v2c (= llr[var(e)]) there.
__global__ void build_kernel(const int* __restrict__ edge_var,
                             const int* __restrict__ edge_chk,
                             const float* __restrict__ llr,
                             int* __restrict__ cnt,
                             int* __restrict__ pos,
                             float* __restrict__ v2c,
                             int E) {
    int e = blockIdx.x * blockDim.x + threadIdx.x;
    if (e >= E) return;
    int c = edge_chk[e];
    int j = atomicAdd(&cnt[c], 1);
    int slot = c * DC_C + j;
    pos[e] = slot;
    v2c[slot] = llr[edge_var[e]];
}

// Check-node update: per check, min1/min2 over |v2c|, sign product,
// c2v_j = sprod*sgn_j*(relu(raw_j - beta) - alpha). Fully coalesced:
// thread c touches v2c[6c..6c+5], c2v[6c..6c+5].
__global__ void check_kernel(const float* __restrict__ v2c,
                             float* __restrict__ c2v,
                             const float* __restrict__ beta,
                             const float* __restrict__ alpha,
                             int t, int n_chk) {
    int c = blockIdx.x * blockDim.x + threadIdx.x;
    if (c >= n_chk) return;
    float b = beta[t];
    float a = alpha[t];
    float sg[DC_C], mg[DC_C];
    float sprod = 1.0f;
    float m1 = INFINITY, m2 = INFINITY;
#pragma unroll
    for (int j = 0; j < DC_C; ++j) {
        float v = v2c[c * DC_C + j];
        // jnp.sign semantics: sign(0)=0
        float s = (v > 0.0f) ? 1.0f : ((v < 0.0f) ? -1.0f : 0.0f);
        float m = fabsf(v);
        sg[j] = s;
        mg[j] = m;
        sprod *= s;
        if (m < m1) { m2 = m1; m1 = m; }
        else if (m < m2) { m2 = m; }
    }
#pragma unroll
    for (int j = 0; j < DC_C; ++j) {
        // Ties: if mg[j]==m1 for multiple j, then m2==m1, so assigning m2 to
        // all of them is value-identical to the reference's first-argmin rule.
        float raw = (mg[j] == m1) ? m2 : m1;
        float val = fmaxf(raw - b, 0.0f) - a;
        c2v[c * DC_C + j] = sprod * sg[j] * val;
    }
}

// Variable-node update: var v gathers its 3 c2v (edge order 3v,3v+1,3v+2 via
// pos[]), tot = (c0+c1)+c2 (reference segment-sum order), scatters
// v2c_new = (llr+tot) - c2v_self back to check-slot positions.
__global__ void var_kernel(const float* __restrict__ c2v,
                           const int* __restrict__ pos,
                           const float* __restrict__ llr,
                           float* __restrict__ v2c,
                           int n) {
    int v = blockIdx.x * blockDim.x + threadIdx.x;
    if (v >= n) return;
    int p0 = pos[v * 3 + 0];
    int p1 = pos[v * 3 + 1];
    int p2 = pos[v * 3 + 2];
    float c0 = c2v[p0];
    float c1 = c2v[p1];
    float c2 = c2v[p2];
    float tot = (c0 + c1) + c2;
    float t = llr[v] + tot;
    v2c[p0] = t - c0;
    v2c[p1] = t - c1;
    v2c[p2] = t - c2;
}

// Final pass (replaces var update on last iteration): posterior + hard bits.
// Output layout: [0..n)   decoded bits as float 0.0/1.0
//                [n..2n)  posterior f32
__global__ void final_kernel(const float* __restrict__ c2v,
                             const int* __restrict__ pos,
                             const float* __restrict__ llr,
                             float* __restrict__ out,
                             int n) {
    int v = blockIdx.x * blockDim.x + threadIdx.x;
    if (v >= n) return;
    int p0 = pos[v * 3 + 0];
    int p1 = pos[v * 3 + 1];
    int p2 = pos[v * 3 + 2];
    float c0 = c2v[p0];
    float c1 = c2v[p1];
    float c2 = c2v[p2];
    float tot = (c0 + c1) + c2;
    float post = llr[v] + tot;
    out[v] = (post < 0.0f) ? 1.0f : 0.0f;
    out[n + v] = post;
}

extern "C" void kernel_launch(void* const* d_in, const int* in_sizes, int n_in,
                              void* d_out, int out_size, void* d_ws, size_t ws_size,
                              hipStream_t stream) {
    const float* llr      = (const float*)d_in[0];
    const float* beta     = (const float*)d_in[1];
    const float* alpha    = (const float*)d_in[2];
    const int*   edge_var = (const int*)d_in[3];
    const int*   edge_chk = (const int*)d_in[4];
    // d_in[5] is n_checks as a 1-element device array; derive instead (DC=6).

    const int n  = in_sizes[0];       // 524288
    const int T  = in_sizes[1];       // 10
    const int E  = in_sizes[3];       // 1572864
    const int n_chk = E / DC_C;       // 262144

    // Workspace layout (all rebuilt every call; ws is poisoned between calls)
    char* ws = (char*)d_ws;
    int*   cnt = (int*)ws;                                      // n_chk ints (1 MB)
    int*   pos = (int*)(ws + (size_t)n_chk * 4);                // E ints (6 MB)
    float* v2c = (float*)(ws + (size_t)n_chk * 4 + (size_t)E * 4); // E f32 (6 MB)
    float* c2v = v2c + E;                                       // E f32 (6 MB)

    hipMemsetAsync(cnt, 0, (size_t)n_chk * 4, stream);
    build_kernel<<<(E + 255) / 256, 256, 0, stream>>>(edge_var, edge_chk, llr,
                                                      cnt, pos, v2c, E);
    for (int t = 0; t < T; ++t) {
        check_kernel<<<(n_chk + 255) / 256, 256, 0, stream>>>(v2c, c2v, beta,
                                                              alpha, t, n_chk);
        if (t + 1 < T) {
            var_kernel<<<(n + 255) / 256, 256, 0, stream>>>(c2v, pos, llr, v2c, n);
        } else {
            final_kernel<<<(n + 255) / 256, 256, 0, stream>>>(c2v, pos, llr,
                                                              (float*)d_out, n);
        }
    }
}

// Round 2
// 438.656 us; speedup vs baseline: 1.4206x; 1.4206x over previous
//
#include <hip/hip_runtime.h>
#include <math.h>

#define DC_C 6
#define NRANGE 8          // slot ranges, aligned to blockIdx%8 -> XCD round-robin
#define BCH 2048          // edges per block in build_b

// Phase A (all writes coalesced): per edge e, claim slot j in check c via
// atomic, write pos[e] = c*6+j (coalesced), init v2c_e[e] = llr[e/3]
// (coalesced; edge_var[e] == e/3 by construction).
__global__ void build_a(const int* __restrict__ edge_chk,
                        const float* __restrict__ llr,
                        int* __restrict__ cnt,
                        int* __restrict__ pos,
                        float* __restrict__ v2c_e,
                        int E) {
    int e = blockIdx.x * blockDim.x + threadIdx.x;
    if (e >= E) return;
    int c = edge_chk[e];
    int j = atomicAdd(&cnt[c], 1);
    pos[e] = c * DC_C + j;
    v2c_e[e] = llr[e / 3];
}

// Phase B: invert pos -> idx (slot -> edge). The only random write in the
// pipeline. Range-partitioned: blocks with (blockIdx&7)==r write only slots in
// [r*E/8,(r+1)*E/8), so each 64B line of idx is filled by one XCD (round-robin
// heuristic) before writeback -> ~6MB writes instead of ~100MB amplified.
// Cost: pos[] is swept 8x (coalesced, L2/L3-resident).
__global__ void build_b(const int* __restrict__ pos,
                        int* __restrict__ idx,
                        int E) {
    int r = blockIdx.x & (NRANGE - 1);
    int chunk = blockIdx.x >> 3;
    int lo = r * (E / NRANGE);
    int hi = lo + (E / NRANGE);
    int base = chunk * BCH;
    for (int k = threadIdx.x; k < BCH; k += 256) {
        int e = base + k;
        if (e >= E) break;
        int s = pos[e];
        if (s >= lo && s < hi) idx[s] = e;
    }
}

// Check-node update. Thread c: coalesced-ish read of idx[6c..6c+5], random
// gather of v2c_e (L2/L3-resident), coalesced write of c2v_s[6c..6c+5].
__global__ void check_kernel(const float* __restrict__ v2c_e,
                             const int* __restrict__ idx,
                             float* __restrict__ c2v_s,
                             const float* __restrict__ beta,
                             const float* __restrict__ alpha,
                             int t, int n_chk) {
    int c = blockIdx.x * blockDim.x + threadIdx.x;
    if (c >= n_chk) return;
    float b = beta[t];
    float a = alpha[t];
    int base = c * DC_C;
    int e[DC_C];
#pragma unroll
    for (int j = 0; j < DC_C; ++j) e[j] = idx[base + j];
    float sg[DC_C], mg[DC_C];
    float sprod = 1.0f;
    float m1 = INFINITY, m2 = INFINITY;
#pragma unroll
    for (int j = 0; j < DC_C; ++j) {
        float v = v2c_e[e[j]];
        float s = (v > 0.0f) ? 1.0f : ((v < 0.0f) ? -1.0f : 0.0f); // sign(0)=0
        float m = fabsf(v);
        sg[j] = s;
        mg[j] = m;
        sprod *= s;
        if (m < m1) { m2 = m1; m1 = m; }
        else if (m < m2) { m2 = m; }
    }
#pragma unroll
    for (int j = 0; j < DC_C; ++j) {
        // mg[j]==m1 for multiple j implies m2==m1 -> value-identical to the
        // reference's first-argmin tie rule.
        float raw = (mg[j] == m1) ? m2 : m1;
        float val = fmaxf(raw - b, 0.0f) - a;
        c2v_s[base + j] = sprod * sg[j] * val;
    }
}

// Variable-node update. Thread v: coalesced read pos[3v..3v+2] + llr[v],
// random gather of c2v_s, coalesced write v2c_e[3v..3v+2].
__global__ void var_kernel(const float* __restrict__ c2v_s,
                           const int* __restrict__ pos,
                           const float* __restrict__ llr,
                           float* __restrict__ v2c_e,
                           int n) {
    int v = blockIdx.x * blockDim.x + threadIdx.x;
    if (v >= n) return;
    int p0 = pos[v * 3 + 0];
    int p1 = pos[v * 3 + 1];
    int p2 = pos[v * 3 + 2];
    float c0 = c2v_s[p0];
    float c1 = c2v_s[p1];
    float c2 = c2v_s[p2];
    float tot = (c0 + c1) + c2;
    float t = llr[v] + tot;
    v2c_e[v * 3 + 0] = t - c0;
    v2c_e[v * 3 + 1] = t - c1;
    v2c_e[v * 3 + 2] = t - c2;
}

// Final: posterior + hard decision. out[0..n)=bits(as f32), out[n..2n)=posterior.
__global__ void final_kernel(const float* __restrict__ c2v_s,
                             const int* __restrict__ pos,
                             const float* __restrict__ llr,
                             float* __restrict__ out,
                             int n) {
    int v = blockIdx.x * blockDim.x + threadIdx.x;
    if (v >= n) return;
    int p0 = pos[v * 3 + 0];
    int p1 = pos[v * 3 + 1];
    int p2 = pos[v * 3 + 2];
    float c0 = c2v_s[p0];
    float c1 = c2v_s[p1];
    float c2 = c2v_s[p2];
    float post = llr[v] + ((c0 + c1) + c2);
    out[v] = (post < 0.0f) ? 1.0f : 0.0f;
    out[n + v] = post;
}

extern "C" void kernel_launch(void* const* d_in, const int* in_sizes, int n_in,
                              void* d_out, int out_size, void* d_ws, size_t ws_size,
                              hipStream_t stream) {
    const float* llr      = (const float*)d_in[0];
    const float* beta     = (const float*)d_in[1];
    const float* alpha    = (const float*)d_in[2];
    const int*   edge_chk = (const int*)d_in[4];

    const int n  = in_sizes[0];       // 524288
    const int T  = in_sizes[1];       // 10
    const int E  = in_sizes[3];       // 1572864
    const int n_chk = E / DC_C;       // 262144

    // Workspace layout (rebuilt every call; ws re-poisoned between calls)
    char* ws = (char*)d_ws;
    int*   cnt   = (int*)ws;                              // n_chk ints (1 MB)
    int*   pos   = (int*)(ws + (size_t)n_chk * 4);        // E ints  (6 MB)
    int*   idx   = pos + E;                               // E ints  (6 MB)
    float* v2c_e = (float*)(idx + E);                     // E f32   (6 MB)
    float* c2v_s = v2c_e + E;                             // E f32   (6 MB)

    hipMemsetAsync(cnt, 0, (size_t)n_chk * 4, stream);
    build_a<<<(E + 255) / 256, 256, 0, stream>>>(edge_chk, llr, cnt, pos, v2c_e, E);
    {
        int chunks = (E + BCH - 1) / BCH;
        build_b<<<chunks * NRANGE, 256, 0, stream>>>(pos, idx, E);
    }
    for (int t = 0; t < T; ++t) {
        check_kernel<<<(n_chk + 255) / 256, 256, 0, stream>>>(v2c_e, idx, c2v_s,
                                                              beta, alpha, t, n_chk);
        if (t + 1 < T) {
            var_kernel<<<(n + 255) / 256, 256, 0, stream>>>(c2v_s, pos, llr, v2c_e, n);
        } else {
            final_kernel<<<(n + 255) / 256, 256, 0, stream>>>(c2v_s, pos, llr,
                                                              (float*)d_out, n);
        }
    }
}